// Round 10
// baseline (35.641 us; speedup 1.0000x reference)
//
#include <hip/hip_runtime.h>

// YoloLoss — R10: counted-vmcnt two-tile pipeline in 1-wave blocks.
//  * Each 64-thread block handles 2 consecutive tiles. Both tiles' loads
//    (reg loads + LDS-DMA) are issued up front; s_waitcnt vmcnt(15) releases
//    tile A's compute while tile B's 15 VMEM ops stay in flight.
//  * No __syncthreads anywhere (1-wave block): no forced vmcnt(0) drain.
//  * sched_barrier(0) fences pin issue-group order and stop hipcc from
//    hoisting ds_reads above the hand waitcnt (DMA->LDS dep is invisible).
//  * no atomics: per-block partial -> d_ws, tiny reduce kernel.
// Inputs: pred f32[NC,30], tbox f32[NC,4], tcls f32[NC,20], objmap i32[NC].
// Output: d_out[0] = scalar loss (f32).

constexpr int TPB = 64;         // one wave per block; 2 tiles of 64 cells
constexpr float EPSV = 1e-10f;

__device__ __forceinline__ float clamp01(float v) {
    return fminf(fmaxf(v, 0.0f), 1.0f);
}

// async global->LDS, 16B per active lane; LDS dst = wave-uniform base + lane*16
__device__ __forceinline__ void gl_lds16(const float4* g, float4* lds_base) {
    __builtin_amdgcn_global_load_lds(
        (const __attribute__((address_space(1))) void*)g,
        (__attribute__((address_space(3))) void*)lds_base, 16, 0, 0);
}

// full box+BCE for one 64-cell tile; all pred data from lds2, rest in regs
__device__ __forceinline__ float compute_tile(
    const float2* lds2, int t, float4 tb,
    float4 tv0, float4 tv1, float4 tv2, float4 tv3, float4 tv4,
    float objf)
{
    // own-cell box part (10 floats as 5 float2)
    float2 pb[5];
    #pragma unroll
    for (int q = 0; q < 5; ++q) pb[q] = lds2[t * 15 + q];

    // cross-cell BCE operands (20 floats as 10 float2)
    float2 pcl[10];
    int cis[5];
    #pragma unroll
    for (int k = 0; k < 5; ++k) {
        const int j4 = t + k * 64;
        const int ci = j4 / 5;
        const int r  = j4 - ci * 5;
        cis[k] = ci;
        const int b2 = ci * 15 + 5 + 2 * r;
        pcl[2 * k]     = lds2[b2];
        pcl[2 * k + 1] = lds2[b2 + 1];
    }

    const float tx = tb.x, ty = tb.y, tw = tb.z, th = tb.w;
    const float invS = 1.0f / 14.0f;
    const float tcx = tx * invS, tcy = ty * invS;
    const float tww = fmaxf(tw, EPSV), thh = fmaxf(th, EPSV);
    const float tx1 = clamp01(tcx - 0.5f * tww);
    const float ty1 = clamp01(tcy - 0.5f * thh);
    const float tx2 = clamp01(tcx + 0.5f * tww);
    const float ty2 = clamp01(tcy + 0.5f * thh);
    const float tarea = (tx2 - tx1) * (ty2 - ty1);

    const float p0x = pb[0].x, p0y = pb[0].y, p0w = pb[1].x, p0h = pb[1].y;
    const float c0  = pb[2].x;
    const float p1x = pb[2].y, p1y = pb[3].x, p1w = pb[3].y, p1h = pb[4].x;
    const float c1  = pb[4].y;

    float iou0, iou1;
    {
        const float cx = p0x * invS, cy = p0y * invS;
        const float ww = fmaxf(p0w, EPSV), hh = fmaxf(p0h, EPSV);
        const float x1 = clamp01(cx - 0.5f * ww), y1 = clamp01(cy - 0.5f * hh);
        const float x2 = clamp01(cx + 0.5f * ww), y2 = clamp01(cy + 0.5f * hh);
        const float lx = fmaxf(x1, tx1), ly = fmaxf(y1, ty1);
        const float rx = fminf(x2, tx2), ry = fminf(y2, ty2);
        const float inter = fmaxf(rx - lx, 0.0f) * fmaxf(ry - ly, 0.0f);
        const float pa = (x2 - x1) * (y2 - y1);
        iou0 = inter / (pa + tarea - inter + EPSV);
    }
    {
        const float cx = p1x * invS, cy = p1y * invS;
        const float ww = fmaxf(p1w, EPSV), hh = fmaxf(p1h, EPSV);
        const float x1 = clamp01(cx - 0.5f * ww), y1 = clamp01(cy - 0.5f * hh);
        const float x2 = clamp01(cx + 0.5f * ww), y2 = clamp01(cy + 0.5f * hh);
        const float lx = fmaxf(x1, tx1), ly = fmaxf(y1, ty1);
        const float rx = fminf(x2, tx2), ry = fminf(y2, ty2);
        const float inter = fmaxf(rx - lx, 0.0f) * fmaxf(ry - ly, 0.0f);
        const float pa = (x2 - x1) * (y2 - y1);
        iou1 = inter / (pa + tarea - inter + EPSV);
    }

    const float d0 = c0 - 0.05f, d1 = c1 - 0.05f;
    const float noobj = (d0 * d0 + d1 * d1) * (1.0f - objf);

    const bool sel = iou1 > iou0;                    // tie -> box 0
    const float biou = fminf((sel ? iou1 : iou0) + 0.5f, 0.95f);
    const float bx = sel ? p1x : p0x;
    const float by = sel ? p1y : p0y;
    const float bw = sel ? p1w : p0w;
    const float bh = sel ? p1h : p0h;
    const float bc = sel ? c1 : c0;

    const float spw = sqrtf(fabsf(bw) + 1e-6f);
    const float stw = sqrtf(fabsf(tw) + 1e-6f);
    const float sph = sqrtf(fabsf(bh) + 1e-6f);
    const float sth = sqrtf(fabsf(th) + 1e-6f);
    const float dx = bx - tx, dy = by - ty, dw = spw - stw, dh = sph - sth;
    const float reg = dx * dx + dy * dy + dw * dw + dh * dh;
    const float dcf = bc - biou;

    float acc = noobj * 0.5f + (reg * 10.0f + dcf * dcf * 10.0f) * objf;

    // class BCE: -ln2*(lq + t*(lp-lq))
    const float4 tvv[5] = {tv0, tv1, tv2, tv3, tv4};   // static idx after unroll
    float csum = 0.0f;
    #pragma unroll
    for (int k = 0; k < 5; ++k) {
        const float of = __shfl(objf, cis[k]);
        const float pv[4] = {pcl[2 * k].x, pcl[2 * k].y,
                             pcl[2 * k + 1].x, pcl[2 * k + 1].y};
        const float tvf[4] = {tvv[k].x, tvv[k].y, tvv[k].z, tvv[k].w};
        float s = 0.0f;
        #pragma unroll
        for (int u = 0; u < 4; ++u) {
            const float p = fminf(fmaxf(pv[u], 1e-7f), 1.0f - 1e-7f);
            const float lp = __log2f(p);
            const float lq = __log2f(1.0f - p);
            s += lq + tvf[u] * (lp - lq);
        }
        csum += s * of;
    }
    acc += csum * (-0.5f * 0.69314718055994530942f);
    return acc;
}

template <bool ATOMIC>
__global__ __launch_bounds__(TPB, 2) void yolo_part(
    const float* __restrict__ pred,
    const float* __restrict__ tbox,
    const float* __restrict__ tcls,
    const int* __restrict__ objmap,
    float* __restrict__ partial,
    float* __restrict__ out,
    float inv_n)
{
    __shared__ float4 lds_p4[960];   // 2 tiles x 480 float4 = 15360 B

    const int t = threadIdx.x;
    const size_t tileA = (size_t)blockIdx.x * 2;
    const size_t cellA = tileA * 64;
    const size_t cellB = cellA + 64;

    // ---- issue group A: 15 VMEM ops (tb 1, tcls 5, obj 1, DMA 8) ----
    const float4 tbA = reinterpret_cast<const float4*>(tbox)[cellA + t];
    const float4* gtcA = reinterpret_cast<const float4*>(tcls) + cellA * 5;
    const float4 tvA0 = gtcA[t],       tvA1 = gtcA[t + 64],
                 tvA2 = gtcA[t + 128], tvA3 = gtcA[t + 192],
                 tvA4 = gtcA[t + 256];
    const int obA = objmap[cellA + t];
    {
        const float4* gpA = reinterpret_cast<const float4*>(pred) + tileA * 480;
        #pragma unroll
        for (int k = 0; k < 7; ++k) gl_lds16(gpA + k * 64 + t, lds_p4 + k * 64);
        if (t < 32) gl_lds16(gpA + 448 + t, lds_p4 + 448);
    }
    __builtin_amdgcn_sched_barrier(0);

    // ---- issue group B: 15 VMEM ops ----
    const float4 tbB = reinterpret_cast<const float4*>(tbox)[cellB + t];
    const float4* gtcB = reinterpret_cast<const float4*>(tcls) + cellB * 5;
    const float4 tvB0 = gtcB[t],       tvB1 = gtcB[t + 64],
                 tvB2 = gtcB[t + 128], tvB3 = gtcB[t + 192],
                 tvB4 = gtcB[t + 256];
    const int obB = objmap[cellB + t];
    {
        const float4* gpB = reinterpret_cast<const float4*>(pred) +
                            (tileA + 1) * 480;
        #pragma unroll
        for (int k = 0; k < 7; ++k)
            gl_lds16(gpB + k * 64 + t, lds_p4 + 480 + k * 64);
        if (t < 32) gl_lds16(gpB + 448 + t, lds_p4 + 480 + 448);
    }
    __builtin_amdgcn_sched_barrier(0);

    // ---- wait for A only (B's 15 stay in flight under A's compute) ----
    asm volatile("s_waitcnt vmcnt(15)" ::: "memory");
    __builtin_amdgcn_sched_barrier(0);

    const float2* lds2 = reinterpret_cast<const float2*>(lds_p4);
    float acc = compute_tile(lds2, t, tbA, tvA0, tvA1, tvA2, tvA3, tvA4,
                             obA ? 1.0f : 0.0f);
    __builtin_amdgcn_sched_barrier(0);

    // ---- drain B, compute B ----
    asm volatile("s_waitcnt vmcnt(0)" ::: "memory");
    __builtin_amdgcn_sched_barrier(0);
    acc += compute_tile(lds2 + 960, t, tbB, tvB0, tvB1, tvB2, tvB3, tvB4,
                        obB ? 1.0f : 0.0f);

    // ---- wave reduce, one plain store per block ----
    #pragma unroll
    for (int off = 32; off > 0; off >>= 1) acc += __shfl_down(acc, off);
    if (t == 0) {
        if (ATOMIC) atomicAdd(out, acc * inv_n);
        else partial[blockIdx.x] = acc;
    }
}

__global__ __launch_bounds__(256) void yolo_reduce(
    const float* __restrict__ partial, float* __restrict__ out,
    int nblk4, float inv_n)
{
    __shared__ float ws[4];
    const int t = threadIdx.x;
    const float4* p4 = reinterpret_cast<const float4*>(partial);
    float s = 0.0f;
    for (int i = t; i < nblk4; i += 256) {
        const float4 v = p4[i];
        s += (v.x + v.y) + (v.z + v.w);
    }
    #pragma unroll
    for (int off = 32; off > 0; off >>= 1) s += __shfl_down(s, off);
    if ((t & 63) == 0) ws[t >> 6] = s;
    __syncthreads();
    if (t == 0) out[0] = (ws[0] + ws[1] + ws[2] + ws[3]) * inv_n;
}

extern "C" void kernel_launch(void* const* d_in, const int* in_sizes, int n_in,
                              void* d_out, int out_size, void* d_ws, size_t ws_size,
                              hipStream_t stream) {
    const float* pred = (const float*)d_in[0];
    const float* tbox = (const float*)d_in[1];
    const float* tcls = (const float*)d_in[2];
    const int* objmap = (const int*)d_in[3];
    float* out = (float*)d_out;

    const int ncells = in_sizes[3];          // N * S * S (802816)
    const int n_imgs = ncells / 196;         // N (4096)
    const float inv_n = 1.0f / (float)n_imgs;
    const int nblk = ncells / 128;           // 6272 blocks... no: 2 tiles/block
    // each block covers 128 cells -> 802816/128 = 6272? cells/128 = 6272.
    // Correct: blocks = ncells / (2*64) = 6272 / 2? ncells/128 = 6272.

    if (ws_size >= (size_t)(ncells / 128) * sizeof(float)) {
        float* partial = (float*)d_ws;
        yolo_part<false><<<ncells / 128, TPB, 0, stream>>>(
            pred, tbox, tcls, objmap, partial, nullptr, inv_n);
        yolo_reduce<<<1, 256, 0, stream>>>(partial, out, (ncells / 128) / 4,
                                           inv_n);
    } else {
        hipMemsetAsync(out, 0, sizeof(float), stream);
        yolo_part<true><<<ncells / 128, TPB, 0, stream>>>(
            pred, tbox, tcls, objmap, nullptr, out, inv_n);
    }
}

// Round 11
// 34.641 us; speedup vs baseline: 1.0289x; 1.0289x over previous
//
#include <hip/hip_runtime.h>

// YoloLoss — R11: NO-LDS structure. One thread owns one whole cell:
//  * pred record (30 f32 = 120 B) read directly as 15x float2 (stride 120 B,
//    8B-aligned). Per-instruction the wave spans ~60 cache lines, but all 15
//    instructions touch the SAME lines -> L1 serves re-touches, HBM traffic
//    unchanged. tcls as 5x float4 (stride 80 B), tbox/obj coalesced.
//  * zero LDS, zero barriers, zero DMA: compiler freely interleaves all 22
//    loads with compute and keeps them outstanding across the body.
//  * per-WAVE partial stores (no block reduce, no atomics) -> tiny reduce
//    kernel sums 12544 partials.
// Inputs: pred f32[NC,30], tbox f32[NC,4], tcls f32[NC,20], objmap i32[NC].
// Output: d_out[0] = scalar loss (f32).

constexpr int TPB = 256;
constexpr float EPSV = 1e-10f;

__device__ __forceinline__ float clamp01(float v) {
    return fminf(fmaxf(v, 0.0f), 1.0f);
}

template <bool ATOMIC>
__global__ __launch_bounds__(TPB, 4) void yolo_part(
    const float* __restrict__ pred,
    const float* __restrict__ tbox,
    const float* __restrict__ tcls,
    const int* __restrict__ objmap,
    float* __restrict__ partial,
    float* __restrict__ out,
    float inv_n)
{
    const int t = threadIdx.x;
    const size_t cell = (size_t)blockIdx.x * TPB + t;

    // ---- coalesced per-cell loads ----
    const float4 tb = reinterpret_cast<const float4*>(tbox)[cell];
    const int ob = objmap[cell];

    // ---- whole cell record: 15 x float2 (8B-aligned, stride 120 B) ----
    const float2* pp = reinterpret_cast<const float2*>(pred) + cell * 15;
    float2 P0 = pp[0], P1 = pp[1], P2 = pp[2], P3 = pp[3], P4 = pp[4];
    float2 P5 = pp[5], P6 = pp[6], P7 = pp[7], P8 = pp[8], P9 = pp[9];
    float2 P10 = pp[10], P11 = pp[11], P12 = pp[12], P13 = pp[13],
           P14 = pp[14];

    // ---- own-cell class targets: 5 x float4 (16B-aligned, stride 80 B) ----
    const float4* tc = reinterpret_cast<const float4*>(tcls) + cell * 5;
    const float4 T0 = tc[0], T1 = tc[1], T2 = tc[2], T3 = tc[3], T4 = tc[4];

    const float objf = ob ? 1.0f : 0.0f;
    const float tx = tb.x, ty = tb.y, tw = tb.z, th = tb.w;

    // ---- box terms ----
    const float invS = 1.0f / 14.0f;
    const float tcx = tx * invS, tcy = ty * invS;
    const float tww = fmaxf(tw, EPSV), thh = fmaxf(th, EPSV);
    const float tx1 = clamp01(tcx - 0.5f * tww);
    const float ty1 = clamp01(tcy - 0.5f * thh);
    const float tx2 = clamp01(tcx + 0.5f * tww);
    const float ty2 = clamp01(tcy + 0.5f * thh);
    const float tarea = (tx2 - tx1) * (ty2 - ty1);

    const float p0x = P0.x, p0y = P0.y, p0w = P1.x, p0h = P1.y, c0 = P2.x;
    const float p1x = P2.y, p1y = P3.x, p1w = P3.y, p1h = P4.x, c1 = P4.y;

    float iou0, iou1;
    {
        const float cx = p0x * invS, cy = p0y * invS;
        const float ww = fmaxf(p0w, EPSV), hh = fmaxf(p0h, EPSV);
        const float x1 = clamp01(cx - 0.5f * ww), y1 = clamp01(cy - 0.5f * hh);
        const float x2 = clamp01(cx + 0.5f * ww), y2 = clamp01(cy + 0.5f * hh);
        const float lx = fmaxf(x1, tx1), ly = fmaxf(y1, ty1);
        const float rx = fminf(x2, tx2), ry = fminf(y2, ty2);
        const float inter = fmaxf(rx - lx, 0.0f) * fmaxf(ry - ly, 0.0f);
        const float pa = (x2 - x1) * (y2 - y1);
        iou0 = inter / (pa + tarea - inter + EPSV);
    }
    {
        const float cx = p1x * invS, cy = p1y * invS;
        const float ww = fmaxf(p1w, EPSV), hh = fmaxf(p1h, EPSV);
        const float x1 = clamp01(cx - 0.5f * ww), y1 = clamp01(cy - 0.5f * hh);
        const float x2 = clamp01(cx + 0.5f * ww), y2 = clamp01(cy + 0.5f * hh);
        const float lx = fmaxf(x1, tx1), ly = fmaxf(y1, ty1);
        const float rx = fminf(x2, tx2), ry = fminf(y2, ty2);
        const float inter = fmaxf(rx - lx, 0.0f) * fmaxf(ry - ly, 0.0f);
        const float pa = (x2 - x1) * (y2 - y1);
        iou1 = inter / (pa + tarea - inter + EPSV);
    }

    const float d0 = c0 - 0.05f, d1 = c1 - 0.05f;
    const float noobj = (d0 * d0 + d1 * d1) * (1.0f - objf);

    const bool sel = iou1 > iou0;                    // tie -> box 0
    const float biou = fminf((sel ? iou1 : iou0) + 0.5f, 0.95f);
    const float bx = sel ? p1x : p0x;
    const float by = sel ? p1y : p0y;
    const float bw = sel ? p1w : p0w;
    const float bh = sel ? p1h : p0h;
    const float bc = sel ? c1 : c0;

    const float spw = sqrtf(fabsf(bw) + 1e-6f);
    const float stw = sqrtf(fabsf(tw) + 1e-6f);
    const float sph = sqrtf(fabsf(bh) + 1e-6f);
    const float sth = sqrtf(fabsf(th) + 1e-6f);
    const float dx = bx - tx, dy = by - ty, dw = spw - stw, dh = sph - sth;
    const float reg = dx * dx + dy * dy + dw * dw + dh * dh;
    const float dcf = bc - biou;

    float acc = noobj * 0.5f + (reg * 10.0f + dcf * dcf * 10.0f) * objf;

    // ---- class BCE, own cell, all static indices:
    //      bce = -ln2*(lq + t*(lp-lq)), lp=log2(p), lq=log2(1-p) ----
    float csum = 0.0f;
    {
        const float2 pa2[10] = {P5, P6, P7, P8, P9, P10, P11, P12, P13, P14};
        const float4 tt[5] = {T0, T1, T2, T3, T4};
        #pragma unroll
        for (int k = 0; k < 5; ++k) {
            const float pv[4] = {pa2[2 * k].x, pa2[2 * k].y,
                                 pa2[2 * k + 1].x, pa2[2 * k + 1].y};
            const float tvf[4] = {tt[k].x, tt[k].y, tt[k].z, tt[k].w};
            #pragma unroll
            for (int u = 0; u < 4; ++u) {
                const float p = fminf(fmaxf(pv[u], 1e-7f), 1.0f - 1e-7f);
                const float lp = __log2f(p);
                const float lq = __log2f(1.0f - p);
                csum += lq + tvf[u] * (lp - lq);
            }
        }
    }
    acc += csum * objf * (-0.5f * 0.69314718055994530942f);

    // ---- wave reduce; per-WAVE partial store (no barrier, no LDS) ----
    #pragma unroll
    for (int off = 32; off > 0; off >>= 1) acc += __shfl_down(acc, off);
    if ((t & 63) == 0) {
        if (ATOMIC) atomicAdd(out, acc * inv_n);
        else partial[blockIdx.x * 4 + (t >> 6)] = acc;
    }
}

__global__ __launch_bounds__(1024) void yolo_reduce(
    const float* __restrict__ partial, float* __restrict__ out,
    int np4, float inv_n)
{
    __shared__ float ws[16];
    const int t = threadIdx.x;
    const float4* p4 = reinterpret_cast<const float4*>(partial);
    float s = 0.0f;
    for (int i = t; i < np4; i += 1024) {
        const float4 v = p4[i];
        s += (v.x + v.y) + (v.z + v.w);
    }
    #pragma unroll
    for (int off = 32; off > 0; off >>= 1) s += __shfl_down(s, off);
    if ((t & 63) == 0) ws[t >> 6] = s;
    __syncthreads();
    if (t < 16) {
        s = ws[t];
        #pragma unroll
        for (int off = 8; off > 0; off >>= 1) s += __shfl_down(s, off, 16);
        if (t == 0) out[0] = s * inv_n;
    }
}

extern "C" void kernel_launch(void* const* d_in, const int* in_sizes, int n_in,
                              void* d_out, int out_size, void* d_ws, size_t ws_size,
                              hipStream_t stream) {
    const float* pred = (const float*)d_in[0];
    const float* tbox = (const float*)d_in[1];
    const float* tcls = (const float*)d_in[2];
    const int* objmap = (const int*)d_in[3];
    float* out = (float*)d_out;

    const int ncells = in_sizes[3];          // N * S * S (802816)
    const int n_imgs = ncells / 196;         // N (4096)
    const float inv_n = 1.0f / (float)n_imgs;
    const int nblk = ncells / TPB;           // 3136
    const int npart = nblk * 4;              // 12544 wave partials

    if (ws_size >= (size_t)npart * sizeof(float)) {
        float* partial = (float*)d_ws;
        yolo_part<false><<<nblk, TPB, 0, stream>>>(pred, tbox, tcls, objmap,
                                                   partial, nullptr, inv_n);
        yolo_reduce<<<1, 1024, 0, stream>>>(partial, out, npart / 4, inv_n);
    } else {
        hipMemsetAsync(out, 0, sizeof(float), stream);
        yolo_part<true><<<nblk, TPB, 0, stream>>>(pred, tbox, tcls, objmap,
                                                  nullptr, out, inv_n);
    }
}